// Round 1
// baseline (17400.772 us; speedup 1.0000x reference)
//
#include <hip/hip_runtime.h>

#define NUM_E 38
#define FDIM 1140
#define NPAIRS 50000
#define BM 128            // pairs per block
#define BN 128            // k-outputs per chunk
#define BJ 32             // reduction tile (MFMA K)
#define LSTRIDE 40        // LDS row stride in bf16 units (32 + 8 pad, keeps 16B align)
#define NCHUNK 9          // ceil(1140/128)
#define NJIT 36           // 1152/32 (K padded to 36*32)
#define NTILES 391        // ceil(50000/128)

typedef short short8 __attribute__((ext_vector_type(8)));
typedef short short4v __attribute__((ext_vector_type(4)));
typedef float float4v __attribute__((ext_vector_type(4)));

__device__ __forceinline__ short f2bf(float f) {
  union { float f; unsigned u; } v; v.f = f;
  unsigned r = v.u + 0x7FFFu + ((v.u >> 16) & 1u);   // round-to-nearest-even
  return (short)(r >> 16);
}

// out[e,i] = sum_k start[i,k] * R[i,k],  R[i,k] = sum_j end[i,j] * W[e,k,j]
// GEMM: A = end (m=i, kdim=j, row-major, contiguous j)
//       B^T = W_e (n=k rows, kdim=j cols, natural layout!)  -> no LDS transpose
__global__ void __launch_bounds__(256) kway_kernel(
    const float* __restrict__ start_emb,
    const float* __restrict__ end_emb,
    const float* __restrict__ weights,
    float* __restrict__ out)
{
  __shared__ short lds_a[BM * LSTRIDE];  // end tile  [i_local][j_local]
  __shared__ short lds_b[BN * LSTRIDE];  // W tile    [k_local][j_local]

  const int e  = blockIdx.x % NUM_E;     // e fastest-varying: all W_e stay L3-hot
  const int it = blockIdx.x / NUM_E;
  const int i0 = it * BM;

  const int tid  = threadIdx.x;
  const int wave = tid >> 6;
  const int lane = tid & 63;
  const int l15  = lane & 15;
  const int quad = lane >> 4;

  const float* We = weights + (size_t)e * FDIM * FDIM;

  // staging map: 32 rows x (8 threads * float4 = 32 cols) per round, 4 rounds
  const int srow = tid >> 3;          // 0..31
  const int scol = (tid & 7) << 2;    // 0,4,...,28

  float out_acc[8];                   // [mi*4 + r]
#pragma unroll
  for (int x = 0; x < 8; ++x) out_acc[x] = 0.f;

  for (int nc = 0; nc < NCHUNK; ++nc) {
    const int k0 = nc * BN;

    float4v acc[2][8];                // R fragments: wave rows 32, cols 128
#pragma unroll
    for (int mi = 0; mi < 2; ++mi)
#pragma unroll
      for (int ni = 0; ni < 8; ++ni)
        acc[mi][ni] = (float4v){0.f, 0.f, 0.f, 0.f};

    for (int jt = 0; jt < NJIT; ++jt) {
      const int j0 = jt * BJ;
      const int gj = j0 + scol;
      const bool jok = gj < FDIM;     // F%4==0 so float4 fully valid or fully OOB

      float4v av[4], bv[4];
#pragma unroll
      for (int rr = 0; rr < 4; ++rr) {
        const int row = (rr << 5) + srow;
        const int gi = i0 + row;
        av[rr] = (float4v){0.f, 0.f, 0.f, 0.f};
        if (jok && gi < NPAIRS)
          av[rr] = *(const float4v*)(end_emb + (size_t)gi * FDIM + gj);
        const int gk = k0 + row;
        bv[rr] = (float4v){0.f, 0.f, 0.f, 0.f};
        if (jok && gk < FDIM)
          bv[rr] = *(const float4v*)(We + (size_t)gk * FDIM + gj);
      }

      // previous iteration's frag reads completed at the loop-end barrier
#pragma unroll
      for (int rr = 0; rr < 4; ++rr) {
        const int row = (rr << 5) + srow;
        short4v a4 = { f2bf(av[rr][0]), f2bf(av[rr][1]), f2bf(av[rr][2]), f2bf(av[rr][3]) };
        *(short4v*)(&lds_a[row * LSTRIDE + scol]) = a4;
        short4v b4 = { f2bf(bv[rr][0]), f2bf(bv[rr][1]), f2bf(bv[rr][2]), f2bf(bv[rr][3]) };
        *(short4v*)(&lds_b[row * LSTRIDE + scol]) = b4;
      }
      __syncthreads();

      short8 afrag[2], bfrag[8];
#pragma unroll
      for (int mi = 0; mi < 2; ++mi)
        afrag[mi] = *(short8*)(&lds_a[((wave << 5) + (mi << 4) + l15) * LSTRIDE + (quad << 3)]);
#pragma unroll
      for (int ni = 0; ni < 8; ++ni)
        bfrag[ni] = *(short8*)(&lds_b[((ni << 4) + l15) * LSTRIDE + (quad << 3)]);

#pragma unroll
      for (int mi = 0; mi < 2; ++mi)
#pragma unroll
        for (int ni = 0; ni < 8; ++ni)
          acc[mi][ni] = __builtin_amdgcn_mfma_f32_16x16x32_bf16(
              afrag[mi], bfrag[ni], acc[mi][ni], 0, 0, 0);
      __syncthreads();
    }

    // fused epilogue: out_acc[i] += sum_k R[i,k] * start[i,k] for this k-chunk
    // C/D layout: col = ni*16 + l15 (k), row = wave*32 + mi*16 + quad*4 + r (i)
#pragma unroll
    for (int mi = 0; mi < 2; ++mi) {
#pragma unroll
      for (int r = 0; r < 4; ++r) {
        const int gi = i0 + (wave << 5) + (mi << 4) + (quad << 2) + r;
        const bool iok = gi < NPAIRS;
        float s = 0.f;
#pragma unroll
        for (int ni = 0; ni < 8; ++ni) {
          const int k = k0 + (ni << 4) + l15;
          const float sv = (iok && k < FDIM) ? start_emb[(size_t)gi * FDIM + k] : 0.f;
          s += acc[mi][ni][r] * sv;
        }
        out_acc[(mi << 2) + r] += s;
      }
    }
  }

  // reduce across the 16 column-lanes (xor butterfly stays within the quad-row group)
#pragma unroll
  for (int x = 0; x < 8; ++x) {
    float v = out_acc[x];
    v += __shfl_xor(v, 1);
    v += __shfl_xor(v, 2);
    v += __shfl_xor(v, 4);
    v += __shfl_xor(v, 8);
    out_acc[x] = v;
  }
  if (l15 == 0) {
#pragma unroll
    for (int mi = 0; mi < 2; ++mi)
#pragma unroll
      for (int r = 0; r < 4; ++r) {
        const int gi = i0 + (wave << 5) + (mi << 4) + (quad << 2) + r;
        if (gi < NPAIRS) out[(size_t)e * NPAIRS + gi] = out_acc[(mi << 2) + r];
      }
  }
}

extern "C" void kernel_launch(void* const* d_in, const int* in_sizes, int n_in,
                              void* d_out, int out_size, void* d_ws, size_t ws_size,
                              hipStream_t stream) {
  const float* start_emb = (const float*)d_in[0];
  const float* end_emb   = (const float*)d_in[1];
  const float* weights   = (const float*)d_in[2];
  float* out = (float*)d_out;

  dim3 grid(NUM_E * NTILES);   // 14858 blocks, e fastest-varying
  kway_kernel<<<grid, 256, 0, stream>>>(start_emb, end_emb, weights, out);
}

// Round 2
// 13200.352 us; speedup vs baseline: 1.3182x; 1.3182x over previous
//
#include <hip/hip_runtime.h>

#define NUM_E 38
#define FDIM 1140
#define NPAIRS 50000
#define FPAD 1152           // 1140 padded to 36*32
#define NPAD 50048          // 50000 padded to 391*128
#define BM 128
#define BN 128
#define BJ 32
#define NCHUNK 9            // 1152/128
#define NJIT 36             // 1152/32
#define NTILES 391          // 50048/128

typedef short short8 __attribute__((ext_vector_type(8)));
typedef short short4v __attribute__((ext_vector_type(4)));
typedef float float4v __attribute__((ext_vector_type(4)));

__device__ __forceinline__ short f2bf(float f) {
  union { float f; unsigned u; } v; v.f = f;
  unsigned r = v.u + 0x7FFFu + ((v.u >> 16) & 1u);   // RNE
  return (short)(r >> 16);
}
__device__ __forceinline__ float bf2f(short s) {
  union { unsigned u; float f; } v; v.u = ((unsigned)(unsigned short)s) << 16;
  return v.f;
}
__device__ __forceinline__ void gl2lds16(const short* g, short* l) {
  __builtin_amdgcn_global_load_lds(
      (const __attribute__((address_space(1))) void*)g,
      (__attribute__((address_space(3))) void*)l, 16, 0, 0);
}

// ---- conversion: fp32 [groups][R][C] -> bf16 [groups][Rpad][Cpad], zero-padded
__global__ void __launch_bounds__(256) convpad_kernel(
    const float* __restrict__ src, short* __restrict__ dst,
    int R, int Rpad, int C, int Cpad, int groups)
{
  const int cpc = Cpad >> 3;                       // 8-elem chunks per row
  const long total = (long)groups * Rpad * cpc;
  for (long idx = (long)blockIdx.x * blockDim.x + threadIdx.x; idx < total;
       idx += (long)gridDim.x * blockDim.x) {
    const int g   = (int)(idx / ((long)Rpad * cpc));
    const long rem = idx - (long)g * Rpad * cpc;
    const int row = (int)(rem / cpc);
    const int j0  = ((int)(rem - (long)row * cpc)) << 3;
    short8 o = (short8){0,0,0,0,0,0,0,0};
    if (row < R) {
      const float* s = src + ((size_t)g * R + row) * C + j0;
      if (j0 + 8 <= C) {
        float4v v0 = *(const float4v*)s;
        float4v v1 = *(const float4v*)(s + 4);
        o = (short8){f2bf(v0[0]), f2bf(v0[1]), f2bf(v0[2]), f2bf(v0[3]),
                     f2bf(v1[0]), f2bf(v1[1]), f2bf(v1[2]), f2bf(v1[3])};
      } else {
#pragma unroll
        for (int t = 0; t < 8; ++t)
          o[t] = (j0 + t < C) ? f2bf(s[t]) : (short)0;
      }
    }
    *(short8*)(dst + ((size_t)g * Rpad + row) * Cpad + j0) = o;
  }
}

// ---- main: out[e,i] = sum_k S[i,k] * R[i,k], R = E-tile @ W_e^T via MFMA
__global__ void __launch_bounds__(256) kway_bf16_kernel(
    const short* __restrict__ Wbf,   // [38][1152][1152]
    const short* __restrict__ Sbf,   // [50048][1152]
    const short* __restrict__ Ebf,   // [50048][1152]
    float* __restrict__ out)
{
  __shared__ short lds_a[BM * BJ];   // 8 KB, row-major stride 32, NO pad (glds)
  __shared__ short lds_b[BN * BJ];

  const int e  = blockIdx.x / NTILES;    // e-major: W_e L2-hot, embeddings L3-hot
  const int it = blockIdx.x % NTILES;
  const int i0 = it * BM;

  const int tid  = threadIdx.x;
  const int wave = tid >> 6;
  const int lane = tid & 63;
  const int l15  = lane & 15;
  const int quad = lane >> 4;

  const int sr = lane >> 2;          // 0..15: row within a 16-row slab
  const int sc = (lane & 3) << 3;    // 0,8,16,24: col element

  const short* Abase = Ebf + (size_t)i0 * FPAD;
  const short* Bbase = Wbf + (size_t)e * FPAD * FPAD;

  float out_acc[8];
#pragma unroll
  for (int x = 0; x < 8; ++x) out_acc[x] = 0.f;

  for (int nc = 0; nc < NCHUNK; ++nc) {
    const int k0 = nc << 7;

    float4v acc[2][8];
#pragma unroll
    for (int mi = 0; mi < 2; ++mi)
#pragma unroll
      for (int ni = 0; ni < 8; ++ni)
        acc[mi][ni] = (float4v){0.f, 0.f, 0.f, 0.f};

    for (int jt = 0; jt < NJIT; ++jt) {
      const int j0 = jt << 5;

      // direct global->LDS: per wave-issue 16 rows x 32 cols contiguous
#pragma unroll
      for (int rd = 0; rd < 2; ++rd) {
        const int slab = (wave << 1) + rd;       // 0..7
        const int row  = (slab << 4) + sr;       // 0..127
        gl2lds16(Abase + (size_t)row * FPAD + j0 + sc, lds_a + (slab << 9));
        gl2lds16(Bbase + (size_t)(k0 + row) * FPAD + j0 + sc, lds_b + (slab << 9));
      }
      __syncthreads();

      short8 af[2], bfr[8];
#pragma unroll
      for (int mi = 0; mi < 2; ++mi)
        af[mi] = *(const short8*)(lds_a + (((wave << 5) + (mi << 4) + l15) << 5) + (quad << 3));
#pragma unroll
      for (int ni = 0; ni < 8; ++ni)
        bfr[ni] = *(const short8*)(lds_b + (((ni << 4) + l15) << 5) + (quad << 3));

#pragma unroll
      for (int mi = 0; mi < 2; ++mi)
#pragma unroll
        for (int ni = 0; ni < 8; ++ni)
          acc[mi][ni] = __builtin_amdgcn_mfma_f32_16x16x32_bf16(
              af[mi], bfr[ni], acc[mi][ni], 0, 0, 0);
      __syncthreads();
    }

    // fused epilogue: out_acc += R . start for this k-chunk
    // C/D layout: col(k) = ni*16 + l15, row(i) = wave*32 + mi*16 + quad*4 + r
#pragma unroll
    for (int mi = 0; mi < 2; ++mi) {
#pragma unroll
      for (int r = 0; r < 4; ++r) {
        const int il = (wave << 5) + (mi << 4) + (quad << 2) + r;
        const short* srow = Sbf + (size_t)(i0 + il) * FPAD + k0;
        float s = 0.f;
#pragma unroll
        for (int ni = 0; ni < 8; ++ni)
          s += acc[mi][ni][r] * bf2f(srow[(ni << 4) + l15]);
        out_acc[(mi << 2) + r] += s;
      }
    }
  }

#pragma unroll
  for (int x = 0; x < 8; ++x) {
    float v = out_acc[x];
    v += __shfl_xor(v, 1);
    v += __shfl_xor(v, 2);
    v += __shfl_xor(v, 4);
    v += __shfl_xor(v, 8);
    out_acc[x] = v;
  }
  if (l15 == 0) {
#pragma unroll
    for (int mi = 0; mi < 2; ++mi)
#pragma unroll
      for (int r = 0; r < 4; ++r) {
        const int gi = i0 + (wave << 5) + (mi << 4) + (quad << 2) + r;
        if (gi < NPAIRS) out[(size_t)e * NPAIRS + gi] = out_acc[(mi << 2) + r];
      }
  }
}

// ================= fallback fp32 path (round-1 kernel, known-good) =========
#define LSTRIDE 40
__global__ void __launch_bounds__(256) kway_fp32_kernel(
    const float* __restrict__ start_emb,
    const float* __restrict__ end_emb,
    const float* __restrict__ weights,
    float* __restrict__ out)
{
  __shared__ short lds_a[BM * LSTRIDE];
  __shared__ short lds_b[BN * LSTRIDE];

  const int e  = blockIdx.x % NUM_E;
  const int it = blockIdx.x / NUM_E;
  const int i0 = it * BM;

  const int tid  = threadIdx.x;
  const int wave = tid >> 6;
  const int lane = tid & 63;
  const int l15  = lane & 15;
  const int quad = lane >> 4;

  const float* We = weights + (size_t)e * FDIM * FDIM;
  const int srow = tid >> 3;
  const int scol = (tid & 7) << 2;

  float out_acc[8];
#pragma unroll
  for (int x = 0; x < 8; ++x) out_acc[x] = 0.f;

  for (int nc = 0; nc < NCHUNK; ++nc) {
    const int k0 = nc * BN;
    float4v acc[2][8];
#pragma unroll
    for (int mi = 0; mi < 2; ++mi)
#pragma unroll
      for (int ni = 0; ni < 8; ++ni)
        acc[mi][ni] = (float4v){0.f, 0.f, 0.f, 0.f};

    for (int jt = 0; jt < NJIT; ++jt) {
      const int gj = jt * BJ + scol;
      const bool jok = gj < FDIM;
      float4v av[4], bv[4];
#pragma unroll
      for (int rr = 0; rr < 4; ++rr) {
        const int row = (rr << 5) + srow;
        const int gi = i0 + row;
        av[rr] = (float4v){0.f, 0.f, 0.f, 0.f};
        if (jok && gi < NPAIRS)
          av[rr] = *(const float4v*)(end_emb + (size_t)gi * FDIM + gj);
        const int gk = k0 + row;
        bv[rr] = (float4v){0.f, 0.f, 0.f, 0.f};
        if (jok && gk < FDIM)
          bv[rr] = *(const float4v*)(We + (size_t)gk * FDIM + gj);
      }
#pragma unroll
      for (int rr = 0; rr < 4; ++rr) {
        const int row = (rr << 5) + srow;
        short4v a4 = { f2bf(av[rr][0]), f2bf(av[rr][1]), f2bf(av[rr][2]), f2bf(av[rr][3]) };
        *(short4v*)(&lds_a[row * LSTRIDE + scol]) = a4;
        short4v b4 = { f2bf(bv[rr][0]), f2bf(bv[rr][1]), f2bf(bv[rr][2]), f2bf(bv[rr][3]) };
        *(short4v*)(&lds_b[row * LSTRIDE + scol]) = b4;
      }
      __syncthreads();

      short8 afrag[2], bfrag[8];
#pragma unroll
      for (int mi = 0; mi < 2; ++mi)
        afrag[mi] = *(short8*)(&lds_a[((wave << 5) + (mi << 4) + l15) * LSTRIDE + (quad << 3)]);
#pragma unroll
      for (int ni = 0; ni < 8; ++ni)
        bfrag[ni] = *(short8*)(&lds_b[((ni << 4) + l15) * LSTRIDE + (quad << 3)]);
#pragma unroll
      for (int mi = 0; mi < 2; ++mi)
#pragma unroll
        for (int ni = 0; ni < 8; ++ni)
          acc[mi][ni] = __builtin_amdgcn_mfma_f32_16x16x32_bf16(
              afrag[mi], bfrag[ni], acc[mi][ni], 0, 0, 0);
      __syncthreads();
    }

#pragma unroll
    for (int mi = 0; mi < 2; ++mi) {
#pragma unroll
      for (int r = 0; r < 4; ++r) {
        const int gi = i0 + (wave << 5) + (mi << 4) + (quad << 2) + r;
        const bool iok = gi < NPAIRS;
        float s = 0.f;
#pragma unroll
        for (int ni = 0; ni < 8; ++ni) {
          const int k = k0 + (ni << 4) + l15;
          const float sv = (iok && k < FDIM) ? start_emb[(size_t)gi * FDIM + k] : 0.f;
          s += acc[mi][ni][r] * sv;
        }
        out_acc[(mi << 2) + r] += s;
      }
    }
  }

#pragma unroll
  for (int x = 0; x < 8; ++x) {
    float v = out_acc[x];
    v += __shfl_xor(v, 1);
    v += __shfl_xor(v, 2);
    v += __shfl_xor(v, 4);
    v += __shfl_xor(v, 8);
    out_acc[x] = v;
  }
  if (l15 == 0) {
#pragma unroll
    for (int mi = 0; mi < 2; ++mi)
#pragma unroll
      for (int r = 0; r < 4; ++r) {
        const int gi = i0 + (wave << 5) + (mi << 4) + (quad << 2) + r;
        if (gi < NPAIRS) out[(size_t)e * NPAIRS + gi] = out_acc[(mi << 2) + r];
      }
  }
}

extern "C" void kernel_launch(void* const* d_in, const int* in_sizes, int n_in,
                              void* d_out, int out_size, void* d_ws, size_t ws_size,
                              hipStream_t stream) {
  const float* start_emb = (const float*)d_in[0];
  const float* end_emb   = (const float*)d_in[1];
  const float* weights   = (const float*)d_in[2];
  float* out = (float*)d_out;

  const size_t W_ELEMS = (size_t)NUM_E * FPAD * FPAD;   // 50,429,952
  const size_t EMB_ELEMS = (size_t)NPAD * FPAD;         // 57,655,296
  const size_t need = (W_ELEMS + 2 * EMB_ELEMS) * sizeof(short);  // ~331.5 MB

  if (ws_size >= need) {
    short* Wbf = (short*)d_ws;
    short* Sbf = Wbf + W_ELEMS;
    short* Ebf = Sbf + EMB_ELEMS;

    {
      const long wt = (long)NUM_E * FPAD * (FPAD >> 3);
      convpad_kernel<<<(int)((wt + 255) / 256), 256, 0, stream>>>(
          weights, Wbf, FDIM, FPAD, FDIM, FPAD, NUM_E);
      const long et = (long)NPAD * (FPAD >> 3);
      convpad_kernel<<<(int)((et + 255) / 256), 256, 0, stream>>>(
          start_emb, Sbf, NPAIRS, NPAD, FDIM, FPAD, 1);
      convpad_kernel<<<(int)((et + 255) / 256), 256, 0, stream>>>(
          end_emb, Ebf, NPAIRS, NPAD, FDIM, FPAD, 1);
    }
    kway_bf16_kernel<<<NUM_E * NTILES, 256, 0, stream>>>(Wbf, Sbf, Ebf, out);
  } else {
    kway_fp32_kernel<<<NUM_E * NTILES, 256, 0, stream>>>(
        start_emb, end_emb, weights, out);
  }
}